// Round 6
// baseline (215.292 us; speedup 1.0000x reference)
//
#include <hip/hip_runtime.h>
#include <hip/hip_bf16.h>

// GraphNeuralAssociator: GCN(3 layers, fp32) + all-pairs edge MLP.
// Edge MLP layer 1 factorized: h1(i,j) = relu(Amat[i] + Bmat[j]).
// Layer 2 (68.6 GF) = bf16 MFMA 16x16x32, fp32 accum; layer 3 + sigmoid fused.
// v6: GCN chain was latency-bound at 8 waves/CU (512 blocks x 4 waves).
// New 8x64-tile GEMM -> 1024-2048 blocks (16 waves/CU) per launch.
// rownorm + w2_pack fused into one prep kernel. edge_mlp: + s_setprio(1)
// around MFMA slab (T5; wave role-split stage vs MFMA exists here).

#define NN 512
#define FF 256
#define HH 512

typedef __attribute__((ext_vector_type(8))) short s8v;   // 8 x bf16 bits
typedef __attribute__((ext_vector_type(4))) float f4v;   // MFMA acc

__device__ __forceinline__ ushort f2bf(float f) {
  unsigned u = __float_as_uint(f);
  unsigned r = (u + 0x7fffu + ((u >> 16) & 1u)) >> 16;
  return (ushort)r;
}

// ---------------- prep: rownorm (blocks 0..511) + w2 pack (512..639) --------
__global__ __launch_bounds__(256)
void prep_kernel(const float* __restrict__ adj, float* __restrict__ adjn,
                 const float* __restrict__ w2, ushort* __restrict__ w2t2) {
  int b = blockIdx.x;
  int tid = threadIdx.x;
  if (b < 512) {
    const float* r = adj + b * NN;
    float a0 = r[tid], a1 = r[tid + 256];
    float s = a0 + a1;
#pragma unroll
    for (int m = 1; m < 64; m <<= 1) s += __shfl_xor(s, m);
    __shared__ float wsum[4];
    if ((tid & 63) == 0) wsum[tid >> 6] = s;
    __syncthreads();
    float inv = 1.f / (wsum[0] + wsum[1] + wsum[2] + wsum[3] + 1e-8f);
    float* o = adjn + b * NN;
    o[tid] = a0 * inv;
    o[tid + 256] = a1 * inv;
  } else {
    // w2 -> bf16 pack: w2t2[(k>>5)*16384 + col*32 + (k&31)]
    int b2 = b - 512;                       // 0..127
    int slab = b2 >> 3;                     // 16 slabs of 32 k
    int col = (b2 & 7) * 64 + (tid >> 2);
    int kq = tid & 3;                       // 8-k sub-block
    int k0 = slab * 32 + kq * 8;
    ushort tmp[8];
#pragma unroll
    for (int e = 0; e < 8; ++e) tmp[e] = f2bf(w2[(k0 + e) * HH + col]);
    ushort* dst = w2t2 + slab * 16384 + col * 32 + kq * 8;
    *(ushort4*)dst = *(ushort4*)tmp;
    *(ushort4*)(dst + 4) = *(ushort4*)&tmp[4];
  }
}

// ---------------- fp32 GEMM, 8x64 tile, BK=32, dual-output via z ------------
// C = [relu]( A@B + bias + add ); global->reg prefetch double-buffer.
// 8x64 tiles -> 2-4x more blocks than 16x64 -> 16 waves/CU latency hiding.
template <bool RELU>
__global__ __launch_bounds__(256)
void gemm_ts8(int K,
              const float* __restrict__ A, int lda,
              const float* __restrict__ B0, const float* __restrict__ B1, int ldb,
              const float* __restrict__ bias0, const float* __restrict__ bias1,
              const float* __restrict__ add0, const float* __restrict__ add1, int ldadd,
              float* __restrict__ C0, float* __restrict__ C1, int ldc)
{
  const float* B = blockIdx.z ? B1 : B0;
  const float* bias = blockIdx.z ? bias1 : bias0;
  const float* add = blockIdx.z ? add1 : add0;
  float* C = blockIdx.z ? C1 : C0;
  const int n0 = blockIdx.x * 64;
  const int m0 = blockIdx.y * 8;
  const int tid = threadIdx.x;
  const int row = tid >> 5;       // 0..7 output row
  const int cp = tid & 31;        // col pair -> cols 2cp, 2cp+1

  __shared__ float As[32][9];     // [k][m]
  __shared__ float Bs[32][66];    // [k][n]
  float2 acc = {0.f, 0.f};

  // staging coords
  const int am = tid >> 5, ak = tid & 31;       // A: 8 rows x 32 k
  const int br = tid >> 3, bc = (tid & 7) * 4;  // B: 32 rows x 64 cols (2xf4)

  float pa = A[(m0 + am) * lda + ak];
  float4 pb0 = *(const float4*)&B[br * ldb + n0 + bc];
  float4 pb1 = *(const float4*)&B[br * ldb + n0 + 32 + bc];

  for (int k0 = 0; k0 < K; k0 += 32) {
    As[ak][am] = pa;
    *(float4*)&Bs[br][bc] = pb0;
    *(float4*)&Bs[br][32 + bc] = pb1;
    __syncthreads();
    if (k0 + 32 < K) {
      pa = A[(m0 + am) * lda + k0 + 32 + ak];
      pb0 = *(const float4*)&B[(k0 + 32 + br) * ldb + n0 + bc];
      pb1 = *(const float4*)&B[(k0 + 32 + br) * ldb + n0 + 32 + bc];
    }
#pragma unroll
    for (int k = 0; k < 32; ++k) {
      float a = As[k][row];
      float2 b = *(const float2*)&Bs[k][cp * 2];
      acc.x += a * b.x;
      acc.y += a * b.y;
    }
    __syncthreads();
  }

  int m = m0 + row;
  int col = n0 + cp * 2;
  float2 v = acc;
  if (bias) {
    float2 bv = *(const float2*)&bias[col];
    v.x += bv.x; v.y += bv.y;
  }
  if (add) {
    float2 d = *(const float2*)&add[m * ldadd + col];
    v.x += d.x; v.y += d.y;
  }
  if (RELU) {
    v.x = fmaxf(v.x, 0.f);
    v.y = fmaxf(v.y, 0.f);
  }
  *(float2*)&C[m * ldc + col] = v;
}

// ---------------- fused edge MLP ----------------
// Block = 8 i's x 16 j's = 128 pairs x all 512 cols. 512 threads = 8 waves;
// wave w owns cols [64w, 64w+64): 8 mf x 4 nf fragments (128 acc regs).
// K=512 in 4 chunks of 128, double-buffered LDS (2 x 32 KB, XOR-swizzled).
// LDS padded to 84KB -> 1 block/CU -> 256-reg/thread budget (no spill).
// T14: issue next-chunk loads early, write LDS late. T5: setprio on MFMAs.
__global__ __launch_bounds__(512)
__attribute__((amdgpu_waves_per_eu(2, 2)))
void edge_mlp(const float* __restrict__ Amat, const float* __restrict__ Bmat,
              const ushort* __restrict__ w2t2,
              const float* __restrict__ b2, const float* __restrict__ w3,
              const float* __restrict__ b3,
              float* __restrict__ edges)
{
  __shared__ ushort h1s[2][128 * 128];  // 64 KB
  __shared__ float part[8][640];        // 20 KB (only [8][128] used; pads LDS)

  // exact upper-triangle tile decode: tiles before col-block bj = bj^2+bj
  const int tb = (int)blockIdx.x;
  int bj = (int)((sqrtf(4.f * tb + 1.f) - 1.f) * 0.5f);
  while (bj * bj + bj > tb) --bj;
  while ((bj + 1) * (bj + 2) <= tb) ++bj;
  const int bi = tb - bj * bj - bj;

  const int tid = threadIdx.x;
  const int wid = tid >> 6;
  const int lane = tid & 63;
  const int l15 = lane & 15;
  const int lg = lane >> 4;

  const f4v zero = {0.f, 0.f, 0.f, 0.f};
  f4v acc[8][4];
#pragma unroll
  for (int mf = 0; mf < 8; ++mf)
#pragma unroll
    for (int nf = 0; nf < 4; ++nf) acc[mf][nf] = zero;

  // ---- staged registers (half = 4 q-iters = 32 VGPRs) ----
  float4 sa[4], sb[4];
  auto issue_half = [&](int ch, int h) {  // issue global loads only
#pragma unroll
    for (int q = 0; q < 4; ++q) {
      int fidx = (h * 4 + q) * 512 + tid;
      int p = fidx >> 5;        // pair row 0..127
      int k4 = fidx & 31;       // float4 index within 128-k chunk
      int i = bi * 8 + (p >> 4);
      int j = bj * 16 + (p & 15);
      sa[q] = *(const float4*)(Amat + i * HH + ch * 128 + k4 * 4);
      sb[q] = *(const float4*)(Bmat + j * HH + ch * 128 + k4 * 4);
    }
  };
  auto write_half = [&](int buf, int h) {  // cvt + LDS write (waits on loads)
#pragma unroll
    for (int q = 0; q < 4; ++q) {
      int fidx = (h * 4 + q) * 512 + tid;
      int p = fidx >> 5;
      int k4 = fidx & 31;
      ushort4 pk;
      pk.x = f2bf(fmaxf(sa[q].x + sb[q].x, 0.f));
      pk.y = f2bf(fmaxf(sa[q].y + sb[q].y, 0.f));
      pk.z = f2bf(fmaxf(sa[q].z + sb[q].z, 0.f));
      pk.w = f2bf(fmaxf(sa[q].w + sb[q].w, 0.f));
      int off = (p * 256 + k4 * 8) ^ ((p & 7) << 4);
      *(ushort4*)((char*)h1s[buf] + off) = pk;
    }
  };

  // prologue: stage chunk 0 into buf 0
  issue_half(0, 0); write_half(0, 0);
  issue_half(0, 1); write_half(0, 1);
  __syncthreads();

  // wave's w2 base: cols [64*wid ..), lane l15 col, lane-group lg k-offset
  const ushort* wbase = w2t2 + wid * 2048 + l15 * 32 + lg * 8;

  // rolling w2 prefetch (one 32-k slab ahead, across chunk boundaries)
  s8v nb0, nb1, nb2, nb3;
  nb0 = *(const s8v*)wbase;
  nb1 = *(const s8v*)(wbase + 512);
  nb2 = *(const s8v*)(wbase + 1024);
  nb3 = *(const s8v*)(wbase + 1536);

  // one 32-k slab: 8 ds_reads + 32 MFMAs, rolls w2 prefetch
  auto slab_step = [&](int cur, int slab) {
    s8v cb0 = nb0, cb1 = nb1, cb2 = nb2, cb3 = nb3;
    if (slab < 15) {
      const ushort* wb = wbase + (slab + 1) * 16384;
      nb0 = *(const s8v*)wb;
      nb1 = *(const s8v*)(wb + 512);
      nb2 = *(const s8v*)(wb + 1024);
      nb3 = *(const s8v*)(wb + 1536);
    }
    int ks = slab & 3;
    __builtin_amdgcn_s_setprio(1);
#pragma unroll
    for (int mf = 0; mf < 8; ++mf) {
      int p = mf * 16 + l15;
      int off = (p * 256 + ks * 64 + lg * 16) ^ ((p & 7) << 4);
      s8v a = *(const s8v*)((const char*)h1s[cur] + off);
      acc[mf][0] = __builtin_amdgcn_mfma_f32_16x16x32_bf16(a, cb0, acc[mf][0], 0, 0, 0);
      acc[mf][1] = __builtin_amdgcn_mfma_f32_16x16x32_bf16(a, cb1, acc[mf][1], 0, 0, 0);
      acc[mf][2] = __builtin_amdgcn_mfma_f32_16x16x32_bf16(a, cb2, acc[mf][2], 0, 0, 0);
      acc[mf][3] = __builtin_amdgcn_mfma_f32_16x16x32_bf16(a, cb3, acc[mf][3], 0, 0, 0);
    }
    __builtin_amdgcn_s_setprio(0);
  };

  for (int ch = 0; ch < 4; ++ch) {
    int cur = ch & 1;
    if (ch < 3) issue_half(ch + 1, 0);       // loads in flight under slabs 0-1
    slab_step(cur, ch * 4 + 0);
    slab_step(cur, ch * 4 + 1);
    if (ch < 3) {
      write_half(cur ^ 1, 0);                // counted vmcnt (w2 loads younger)
      issue_half(ch + 1, 1);                 // loads in flight under slabs 2-3
    }
    slab_step(cur, ch * 4 + 2);
    slab_step(cur, ch * 4 + 3);
    if (ch < 3) write_half(cur ^ 1, 1);
    __syncthreads();
  }

  // epilogue: h2 = relu(acc+b2); partial = h2 . w3 over this wave's 64 cols
  float bb[4], ww[4];
#pragma unroll
  for (int nf = 0; nf < 4; ++nf) {
    int col = wid * 64 + nf * 16 + l15;
    bb[nf] = b2[col];
    ww[nf] = w3[col];
  }
#pragma unroll
  for (int mf = 0; mf < 8; ++mf) {
    float ps[4];
#pragma unroll
    for (int e = 0; e < 4; ++e) {
      ps[e] = fmaxf(acc[mf][0][e] + bb[0], 0.f) * ww[0] +
              fmaxf(acc[mf][1][e] + bb[1], 0.f) * ww[1] +
              fmaxf(acc[mf][2][e] + bb[2], 0.f) * ww[2] +
              fmaxf(acc[mf][3][e] + bb[3], 0.f) * ww[3];
    }
#pragma unroll
    for (int m = 1; m < 16; m <<= 1) {
#pragma unroll
      for (int e = 0; e < 4; ++e) ps[e] += __shfl_xor(ps[e], m);
    }
    if (l15 == 0) {
#pragma unroll
      for (int e = 0; e < 4; ++e)
        part[wid][mf * 16 + lg * 4 + e] = ps[e];
    }
  }
  __syncthreads();
  if (tid < 128) {
    float tot = b3[0];
#pragma unroll
    for (int w = 0; w < 8; ++w) tot += part[w][tid];
    float sg = 1.f / (1.f + expf(-tot));
    int i = bi * 8 + (tid >> 4);
    int j = bj * 16 + (tid & 15);
    if (i < j) {
      edges[i * NN + j] = sg;
      edges[j * NN + i] = sg;
    } else if (i == j) {
      edges[i * NN + i] = 0.f;
    }
  }
}

extern "C" void kernel_launch(void* const* d_in, const int* in_sizes, int n_in,
                              void* d_out, int out_size, void* d_ws, size_t ws_size,
                              hipStream_t stream) {
  const float* node = (const float*)d_in[0];
  const float* adj  = (const float*)d_in[1];
  const float* g1wl = (const float*)d_in[2];
  const float* g1bl = (const float*)d_in[3];
  const float* g1ws = (const float*)d_in[4];
  const float* g1bs = (const float*)d_in[5];
  const float* g2wl = (const float*)d_in[6];
  const float* g2bl = (const float*)d_in[7];
  const float* g2ws = (const float*)d_in[8];
  const float* g2bs = (const float*)d_in[9];
  const float* g3wl = (const float*)d_in[10];
  const float* g3bl = (const float*)d_in[11];
  const float* g3ws = (const float*)d_in[12];
  const float* g3bs = (const float*)d_in[13];
  const float* w1 = (const float*)d_in[14];
  const float* b1 = (const float*)d_in[15];
  const float* w2 = (const float*)d_in[16];
  const float* b2 = (const float*)d_in[17];
  const float* w3 = (const float*)d_in[18];
  const float* b3 = (const float*)d_in[19];

  float* out = (float*)d_out;
  float* emb = out;                 // [512][256]
  float* edges = out + NN * FF;     // [512][512]

  char* wsb = (char*)d_ws;
  float* adjn = (float*)wsb;                     // 1 MB
  float* Tb   = (float*)(wsb + (1u << 20));      // 1 MB
  float* Sb   = (float*)(wsb + (2u << 20));      // 1 MB
  float* xa   = (float*)(wsb + (3u << 20));      // 1 MB
  float* xb   = (float*)(wsb + (4u << 20));      // 1 MB
  ushort* w2t2 = (ushort*)(wsb + (5u << 20));    // 512 KB
  float* Amat = Tb;  // reused after GCN
  float* Bmat = Sb;

  // rownorm + w2 pack in one launch
  prep_kernel<<<640, 256, 0, stream>>>(adj, adjn, w2, w2t2);

  // ---- GCN layer 1: T=x@wl+bl, S=x@ws+bs ; xa=relu(adjn@T+S)
  gemm_ts8<false><<<dim3(8, 64, 2), 256, 0, stream>>>(
      FF, node, FF, g1wl, g1ws, HH, g1bl, g1bs,
      nullptr, nullptr, 0, Tb, Sb, HH);
  gemm_ts8<true><<<dim3(8, 64, 1), 256, 0, stream>>>(
      NN, adjn, NN, Tb, Tb, HH, nullptr, nullptr,
      Sb, Sb, HH, xa, xa, HH);
  // ---- GCN layer 2
  gemm_ts8<false><<<dim3(8, 64, 2), 256, 0, stream>>>(
      HH, xa, HH, g2wl, g2ws, HH, g2bl, g2bs,
      nullptr, nullptr, 0, Tb, Sb, HH);
  gemm_ts8<true><<<dim3(8, 64, 1), 256, 0, stream>>>(
      NN, adjn, NN, Tb, Tb, HH, nullptr, nullptr,
      Sb, Sb, HH, xb, xb, HH);
  // ---- GCN layer 3 (no relu) -> emb (d_out)
  gemm_ts8<false><<<dim3(4, 64, 2), 256, 0, stream>>>(
      HH, xb, HH, g3wl, g3ws, FF, g3bl, g3bs,
      nullptr, nullptr, 0, Tb, Sb, FF);
  gemm_ts8<false><<<dim3(4, 64, 1), 256, 0, stream>>>(
      NN, adjn, NN, Tb, Tb, FF, nullptr, nullptr,
      Sb, Sb, FF, emb, emb, FF);

  // ---- edge MLP layer-1 factorization: Amat = emb@w1_top+b1, Bmat = emb@w1_bot
  gemm_ts8<false><<<dim3(8, 64, 2), 256, 0, stream>>>(
      FF, emb, FF, w1, w1 + FF * HH, HH, b1, nullptr,
      nullptr, nullptr, 0, Amat, Bmat, HH);

  // ---- fused edge MLP: exact triangular grid (32^2 + 32 = 1056 tiles)
  edge_mlp<<<1056, 512, 0, stream>>>(Amat, Bmat, w2t2, b2, w3, b3, edges);
}

// Round 7
// 194.194 us; speedup vs baseline: 1.1086x; 1.1086x over previous
//
#include <hip/hip_runtime.h>
#include <hip/hip_bf16.h>

// GraphNeuralAssociator: GCN(3 layers, fp32) + all-pairs edge MLP.
// Edge MLP layer 1 factorized: h1(i,j) = relu(Amat[i] + Bmat[j]).
// Layer 2 (68.6 GF) = bf16 MFMA 16x16x32, fp32 accum; layer 3 + sigmoid fused.
// v7: (a) revert GCN GEMM to 16x64/BK=32 (8x64 regressed: 2 outputs/thread ->
// barrier-bound). (b) edge_mlp: phase-lock waves with one s_barrier per 32-k
// slab before the MFMA cluster (m201-style). Waves previously drifted and
// serialized at the chunk __syncthreads (MfmaUtil 29% with ~70% slack at the
// fixed 2 waves/SIMD occupancy); barriers make MFMA regions overlap.

#define NN 512
#define FF 256
#define HH 512

typedef __attribute__((ext_vector_type(8))) short s8v;   // 8 x bf16 bits
typedef __attribute__((ext_vector_type(4))) float f4v;   // MFMA acc

__device__ __forceinline__ ushort f2bf(float f) {
  unsigned u = __float_as_uint(f);
  unsigned r = (u + 0x7fffu + ((u >> 16) & 1u)) >> 16;
  return (ushort)r;
}

// ---------------- prep: rownorm (blocks 0..511) + w2 pack (512..639) --------
__global__ __launch_bounds__(256)
void prep_kernel(const float* __restrict__ adj, float* __restrict__ adjn,
                 const float* __restrict__ w2, ushort* __restrict__ w2t2) {
  int b = blockIdx.x;
  int tid = threadIdx.x;
  if (b < 512) {
    const float* r = adj + b * NN;
    float a0 = r[tid], a1 = r[tid + 256];
    float s = a0 + a1;
#pragma unroll
    for (int m = 1; m < 64; m <<= 1) s += __shfl_xor(s, m);
    __shared__ float wsum[4];
    if ((tid & 63) == 0) wsum[tid >> 6] = s;
    __syncthreads();
    float inv = 1.f / (wsum[0] + wsum[1] + wsum[2] + wsum[3] + 1e-8f);
    float* o = adjn + b * NN;
    o[tid] = a0 * inv;
    o[tid + 256] = a1 * inv;
  } else {
    // w2 -> bf16 pack: w2t2[(k>>5)*16384 + col*32 + (k&31)]
    int b2 = b - 512;                       // 0..127
    int slab = b2 >> 3;                     // 16 slabs of 32 k
    int col = (b2 & 7) * 64 + (tid >> 2);
    int kq = tid & 3;                       // 8-k sub-block
    int k0 = slab * 32 + kq * 8;
    ushort tmp[8];
#pragma unroll
    for (int e = 0; e < 8; ++e) tmp[e] = f2bf(w2[(k0 + e) * HH + col]);
    ushort* dst = w2t2 + slab * 16384 + col * 32 + kq * 8;
    *(ushort4*)dst = *(ushort4*)tmp;
    *(ushort4*)(dst + 4) = *(ushort4*)&tmp[4];
  }
}

// ---------------- fp32 GEMM, 16x64 tile, BK=32, dual-output via z ----------
// C = [relu]( A@B + bias + add ); global->reg prefetch double-buffer.
template <bool RELU>
__global__ __launch_bounds__(256)
void gemm_ts(int M, int N, int K,
             const float* __restrict__ A, int lda,
             const float* __restrict__ B0, const float* __restrict__ B1, int ldb,
             const float* __restrict__ bias0, const float* __restrict__ bias1,
             const float* __restrict__ add0, const float* __restrict__ add1, int ldadd,
             float* __restrict__ C0, float* __restrict__ C1, int ldc)
{
  const float* B = blockIdx.z ? B1 : B0;
  const float* bias = blockIdx.z ? bias1 : bias0;
  const float* add = blockIdx.z ? add1 : add0;
  float* C = blockIdx.z ? C1 : C0;
  const int n0 = blockIdx.x * 64;
  const int m0 = blockIdx.y * 16;
  const int tid = threadIdx.x;
  const int ty = tid >> 4, tx = tid & 15;

  __shared__ float As[32][18];  // [k][m]
  __shared__ float Bs[32][68];  // [k][n]
  float4 acc = {0.f, 0.f, 0.f, 0.f};

  const int am = tid >> 4;      // A row 0..15
  const int ak = tid & 15;      // k float2 index
  const int bk = tid >> 4;      // B rows bk, bk+16
  const int bn = tid & 15;      // col float4 index

  float2 pa = *(const float2*)&A[(m0 + am) * lda + ak * 2];
  float4 pb0 = *(const float4*)&B[bk * ldb + n0 + bn * 4];
  float4 pb1 = *(const float4*)&B[(bk + 16) * ldb + n0 + bn * 4];

  for (int k0 = 0; k0 < K; k0 += 32) {
    As[ak * 2][am] = pa.x;
    As[ak * 2 + 1][am] = pa.y;
    *(float4*)&Bs[bk][bn * 4] = pb0;
    *(float4*)&Bs[bk + 16][bn * 4] = pb1;
    __syncthreads();
    if (k0 + 32 < K) {  // next-chunk loads hide under FMAs
      pa = *(const float2*)&A[(m0 + am) * lda + k0 + 32 + ak * 2];
      pb0 = *(const float4*)&B[(k0 + 32 + bk) * ldb + n0 + bn * 4];
      pb1 = *(const float4*)&B[(k0 + 48 + bk) * ldb + n0 + bn * 4];
    }
#pragma unroll
    for (int k = 0; k < 32; ++k) {
      float a = As[k][ty];
      float4 b = *(const float4*)&Bs[k][tx * 4];
      acc.x += a * b.x; acc.y += a * b.y; acc.z += a * b.z; acc.w += a * b.w;
    }
    __syncthreads();
  }

  int m = m0 + ty;
  float4 v = acc;
  if (bias) {
    float4 bv = *(const float4*)&bias[n0 + tx * 4];
    v.x += bv.x; v.y += bv.y; v.z += bv.z; v.w += bv.w;
  }
  if (add) {
    float4 d = *(const float4*)&add[m * ldadd + n0 + tx * 4];
    v.x += d.x; v.y += d.y; v.z += d.z; v.w += d.w;
  }
  if (RELU) {
    v.x = fmaxf(v.x, 0.f); v.y = fmaxf(v.y, 0.f);
    v.z = fmaxf(v.z, 0.f); v.w = fmaxf(v.w, 0.f);
  }
  *(float4*)&C[m * ldc + n0 + tx * 4] = v;
}

// ---------------- fused edge MLP ----------------
// Block = 8 i's x 16 j's = 128 pairs x all 512 cols. 512 threads = 8 waves;
// wave w owns cols [64w, 64w+64): 8 mf x 4 nf fragments (128 acc regs).
// K=512 in 4 chunks of 128, double-buffered LDS (2 x 32 KB, XOR-swizzled).
// LDS padded to 84KB -> 1 block/CU -> 256-reg/thread budget (no spill).
// T14: issue next-chunk loads early, write LDS late. T5: setprio on MFMAs.
// v7: phase-lock — one s_barrier per 32-k slab right before the MFMA cluster.
__global__ __launch_bounds__(512)
__attribute__((amdgpu_waves_per_eu(2, 2)))
void edge_mlp(const float* __restrict__ Amat, const float* __restrict__ Bmat,
              const ushort* __restrict__ w2t2,
              const float* __restrict__ b2, const float* __restrict__ w3,
              const float* __restrict__ b3,
              float* __restrict__ edges)
{
  __shared__ ushort h1s[2][128 * 128];  // 64 KB
  __shared__ float part[8][640];        // 20 KB (only [8][128] used; pads LDS)

  // exact upper-triangle tile decode: tiles before col-block bj = bj^2+bj
  const int tb = (int)blockIdx.x;
  int bj = (int)((sqrtf(4.f * tb + 1.f) - 1.f) * 0.5f);
  while (bj * bj + bj > tb) --bj;
  while ((bj + 1) * (bj + 2) <= tb) ++bj;
  const int bi = tb - bj * bj - bj;

  const int tid = threadIdx.x;
  const int wid = tid >> 6;
  const int lane = tid & 63;
  const int l15 = lane & 15;
  const int lg = lane >> 4;

  const f4v zero = {0.f, 0.f, 0.f, 0.f};
  f4v acc[8][4];
#pragma unroll
  for (int mf = 0; mf < 8; ++mf)
#pragma unroll
    for (int nf = 0; nf < 4; ++nf) acc[mf][nf] = zero;

  // ---- staged registers (half = 4 q-iters = 32 VGPRs) ----
  float4 sa[4], sb[4];
  auto issue_half = [&](int ch, int h) {  // issue global loads only
#pragma unroll
    for (int q = 0; q < 4; ++q) {
      int fidx = (h * 4 + q) * 512 + tid;
      int p = fidx >> 5;        // pair row 0..127
      int k4 = fidx & 31;       // float4 index within 128-k chunk
      int i = bi * 8 + (p >> 4);
      int j = bj * 16 + (p & 15);
      sa[q] = *(const float4*)(Amat + i * HH + ch * 128 + k4 * 4);
      sb[q] = *(const float4*)(Bmat + j * HH + ch * 128 + k4 * 4);
    }
  };
  auto write_half = [&](int buf, int h) {  // cvt + LDS write (waits on loads)
#pragma unroll
    for (int q = 0; q < 4; ++q) {
      int fidx = (h * 4 + q) * 512 + tid;
      int p = fidx >> 5;
      int k4 = fidx & 31;
      ushort4 pk;
      pk.x = f2bf(fmaxf(sa[q].x + sb[q].x, 0.f));
      pk.y = f2bf(fmaxf(sa[q].y + sb[q].y, 0.f));
      pk.z = f2bf(fmaxf(sa[q].z + sb[q].z, 0.f));
      pk.w = f2bf(fmaxf(sa[q].w + sb[q].w, 0.f));
      int off = (p * 256 + k4 * 8) ^ ((p & 7) << 4);
      *(ushort4*)((char*)h1s[buf] + off) = pk;
    }
  };

  // prologue: stage chunk 0 into buf 0
  issue_half(0, 0); write_half(0, 0);
  issue_half(0, 1); write_half(0, 1);
  __syncthreads();

  // wave's w2 base: cols [64*wid ..), lane l15 col, lane-group lg k-offset
  const ushort* wbase = w2t2 + wid * 2048 + l15 * 32 + lg * 8;

  // rolling w2 prefetch (one 32-k slab ahead, across chunk boundaries)
  s8v nb0, nb1, nb2, nb3;
  nb0 = *(const s8v*)wbase;
  nb1 = *(const s8v*)(wbase + 512);
  nb2 = *(const s8v*)(wbase + 1024);
  nb3 = *(const s8v*)(wbase + 1536);

  // one 32-k slab: pre-loads, phase barrier, then 8 ds_reads + 32 MFMAs
  auto slab_step = [&](int cur, int slab) {
    s8v cb0 = nb0, cb1 = nb1, cb2 = nb2, cb3 = nb3;
    if (slab < 15) {
      const ushort* wb = wbase + (slab + 1) * 16384;
      nb0 = *(const s8v*)wb;
      nb1 = *(const s8v*)(wb + 512);
      nb2 = *(const s8v*)(wb + 1024);
      nb3 = *(const s8v*)(wb + 1536);
    }
    int ks = slab & 3;
    __builtin_amdgcn_s_barrier();     // phase-lock: all waves enter MFMA together
    __builtin_amdgcn_s_setprio(1);
#pragma unroll
    for (int mf = 0; mf < 8; ++mf) {
      int p = mf * 16 + l15;
      int off = (p * 256 + ks * 64 + lg * 16) ^ ((p & 7) << 4);
      s8v a = *(const s8v*)((const char*)h1s[cur] + off);
      acc[mf][0] = __builtin_amdgcn_mfma_f32_16x16x32_bf16(a, cb0, acc[mf][0], 0, 0, 0);
      acc[mf][1] = __builtin_amdgcn_mfma_f32_16x16x32_bf16(a, cb1, acc[mf][1], 0, 0, 0);
      acc[mf][2] = __builtin_amdgcn_mfma_f32_16x16x32_bf16(a, cb2, acc[mf][2], 0, 0, 0);
      acc[mf][3] = __builtin_amdgcn_mfma_f32_16x16x32_bf16(a, cb3, acc[mf][3], 0, 0, 0);
    }
    __builtin_amdgcn_s_setprio(0);
  };

  for (int ch = 0; ch < 4; ++ch) {
    int cur = ch & 1;
    if (ch < 3) issue_half(ch + 1, 0);       // loads in flight under slabs 0-1
    slab_step(cur, ch * 4 + 0);
    slab_step(cur, ch * 4 + 1);
    if (ch < 3) {
      write_half(cur ^ 1, 0);                // counted vmcnt (w2 loads younger)
      issue_half(ch + 1, 1);                 // loads in flight under slabs 2-3
    }
    slab_step(cur, ch * 4 + 2);
    slab_step(cur, ch * 4 + 3);
    if (ch < 3) write_half(cur ^ 1, 1);
    __syncthreads();
  }

  // epilogue: h2 = relu(acc+b2); partial = h2 . w3 over this wave's 64 cols
  float bb[4], ww[4];
#pragma unroll
  for (int nf = 0; nf < 4; ++nf) {
    int col = wid * 64 + nf * 16 + l15;
    bb[nf] = b2[col];
    ww[nf] = w3[col];
  }
#pragma unroll
  for (int mf = 0; mf < 8; ++mf) {
    float ps[4];
#pragma unroll
    for (int e = 0; e < 4; ++e) {
      ps[e] = fmaxf(acc[mf][0][e] + bb[0], 0.f) * ww[0] +
              fmaxf(acc[mf][1][e] + bb[1], 0.f) * ww[1] +
              fmaxf(acc[mf][2][e] + bb[2], 0.f) * ww[2] +
              fmaxf(acc[mf][3][e] + bb[3], 0.f) * ww[3];
    }
#pragma unroll
    for (int m = 1; m < 16; m <<= 1) {
#pragma unroll
      for (int e = 0; e < 4; ++e) ps[e] += __shfl_xor(ps[e], m);
    }
    if (l15 == 0) {
#pragma unroll
      for (int e = 0; e < 4; ++e)
        part[wid][mf * 16 + lg * 4 + e] = ps[e];
    }
  }
  __syncthreads();
  if (tid < 128) {
    float tot = b3[0];
#pragma unroll
    for (int w = 0; w < 8; ++w) tot += part[w][tid];
    float sg = 1.f / (1.f + expf(-tot));
    int i = bi * 8 + (tid >> 4);
    int j = bj * 16 + (tid & 15);
    if (i < j) {
      edges[i * NN + j] = sg;
      edges[j * NN + i] = sg;
    } else if (i == j) {
      edges[i * NN + i] = 0.f;
    }
  }
}

extern "C" void kernel_launch(void* const* d_in, const int* in_sizes, int n_in,
                              void* d_out, int out_size, void* d_ws, size_t ws_size,
                              hipStream_t stream) {
  const float* node = (const float*)d_in[0];
  const float* adj  = (const float*)d_in[1];
  const float* g1wl = (const float*)d_in[2];
  const float* g1bl = (const float*)d_in[3];
  const float* g1ws = (const float*)d_in[4];
  const float* g1bs = (const float*)d_in[5];
  const float* g2wl = (const float*)d_in[6];
  const float* g2bl = (const float*)d_in[7];
  const float* g2ws = (const float*)d_in[8];
  const float* g2bs = (const float*)d_in[9];
  const float* g3wl = (const float*)d_in[10];
  const float* g3bl = (const float*)d_in[11];
  const float* g3ws = (const float*)d_in[12];
  const float* g3bs = (const float*)d_in[13];
  const float* w1 = (const float*)d_in[14];
  const float* b1 = (const float*)d_in[15];
  const float* w2 = (const float*)d_in[16];
  const float* b2 = (const float*)d_in[17];
  const float* w3 = (const float*)d_in[18];
  const float* b3 = (const float*)d_in[19];

  float* out = (float*)d_out;
  float* emb = out;                 // [512][256]
  float* edges = out + NN * FF;     // [512][512]

  char* wsb = (char*)d_ws;
  float* adjn = (float*)wsb;                     // 1 MB
  float* Tb   = (float*)(wsb + (1u << 20));      // 1 MB
  float* Sb   = (float*)(wsb + (2u << 20));      // 1 MB
  float* xa   = (float*)(wsb + (3u << 20));      // 1 MB
  float* xb   = (float*)(wsb + (4u << 20));      // 1 MB
  ushort* w2t2 = (ushort*)(wsb + (5u << 20));    // 512 KB
  float* Amat = Tb;  // reused after GCN
  float* Bmat = Sb;

  // rownorm + w2 pack in one launch
  prep_kernel<<<640, 256, 0, stream>>>(adj, adjn, w2, w2t2);

  // ---- GCN layer 1: T=x@wl+bl, S=x@ws+bs ; xa=relu(adjn@T+S)
  gemm_ts<false><<<dim3(8, 32, 2), 256, 0, stream>>>(
      NN, HH, FF, node, FF, g1wl, g1ws, HH, g1bl, g1bs,
      nullptr, nullptr, 0, Tb, Sb, HH);
  gemm_ts<true><<<dim3(8, 32, 1), 256, 0, stream>>>(
      NN, HH, NN, adjn, NN, Tb, Tb, HH, nullptr, nullptr,
      Sb, Sb, HH, xa, xa, HH);
  // ---- GCN layer 2
  gemm_ts<false><<<dim3(8, 32, 2), 256, 0, stream>>>(
      NN, HH, HH, xa, HH, g2wl, g2ws, HH, g2bl, g2bs,
      nullptr, nullptr, 0, Tb, Sb, HH);
  gemm_ts<true><<<dim3(8, 32, 1), 256, 0, stream>>>(
      NN, HH, NN, adjn, NN, Tb, Tb, HH, nullptr, nullptr,
      Sb, Sb, HH, xb, xb, HH);
  // ---- GCN layer 3 (no relu) -> emb (d_out)
  gemm_ts<false><<<dim3(4, 32, 2), 256, 0, stream>>>(
      NN, FF, HH, xb, HH, g3wl, g3ws, FF, g3bl, g3bs,
      nullptr, nullptr, 0, Tb, Sb, FF);
  gemm_ts<false><<<dim3(4, 32, 1), 256, 0, stream>>>(
      NN, FF, NN, adjn, NN, Tb, Tb, FF, nullptr, nullptr,
      Sb, Sb, FF, emb, emb, FF);

  // ---- edge MLP layer-1 factorization: Amat = emb@w1_top+b1, Bmat = emb@w1_bot
  gemm_ts<false><<<dim3(8, 32, 2), 256, 0, stream>>>(
      NN, HH, FF, emb, FF, w1, w1 + FF * HH, HH, b1, nullptr,
      nullptr, nullptr, 0, Amat, Bmat, HH);

  // ---- fused edge MLP: exact triangular grid (32^2 + 32 = 1056 tiles)
  edge_mlp<<<1056, 512, 0, stream>>>(Amat, Bmat, w2t2, b2, w3, b3, edges);
}